// Round 9
// baseline (602.654 us; speedup 1.0000x reference)
//
#include <hip/hip_runtime.h>
#include <cmath>

// B=8, N=512, V=8000, H=256
// Algebraic fusion: xw = inputs @ W2 + c2, where W2 = emb_w@wx, c2 = emb_b@wx + hb.
// Pipeline (7 dispatches):
//   k_prep:     wh->whT, wx->wxT (bf16 transposes, 32 blocks) + c2 (1 block)
//   k_w2m:      W2T[h][v] = (wxT @ emb_w^T) via MFMA
//   k_embed_gemm2: part[kc][4096][256] = inputs @ W2  (bf16 MFMA, KSPLIT=5)
//   k_reduce2:  xw4[b][t][h] = sum_kc part + c2
//   k_rnn_scan: 512 steps, per-batch blocks (8), 4 waves, wh in regs,
//               4 MFMA chains of depth 2, single raw barrier/step
//   k_logits / k_softmax8

typedef float f32x4 __attribute__((ext_vector_type(4)));
typedef __bf16 bf16x4 __attribute__((ext_vector_type(4)));
typedef __bf16 bf16x8 __attribute__((ext_vector_type(8)));

#define KSPLIT 5
#define KCH 1600
#define NITER 25   // KCH / 64

// ---------------- prep: transpose wh,wx to bf16 + c2 ----------------
// grid 33 blocks x 256 thr: blocks 0..15 = wh tiles, 16..31 = wx tiles, 32 = c2
__global__ __launch_bounds__(256) void k_prep(const float* __restrict__ wh,
                                              const float* __restrict__ wx,
                                              const float* __restrict__ emb_b,
                                              const float* __restrict__ hb,
                                              __bf16* __restrict__ whT,
                                              __bf16* __restrict__ wxT,
                                              float* __restrict__ c2) {
  const int blk = blockIdx.x;
  const int tid = threadIdx.x;
  if (blk == 32) {
    const int h = tid;
    float s = hb[h];
#pragma unroll 8
    for (int k = 0; k < 256; ++k) s += emb_b[k] * wx[k * 256 + h];
    c2[h] = s;
    return;
  }
  __shared__ __bf16 lt[64][72];
  const float* in = (blk < 16) ? wh : wx;
  __bf16* out = (blk < 16) ? whT : wxT;
  const int t4 = blk & 15;
  const int r0 = (t4 & 3) * 64, c0 = (t4 >> 2) * 64;
  {
    const int rr = tid >> 2, cg = (tid & 3) * 16;
    const float* src = &in[(size_t)(r0 + rr) * 256 + c0 + cg];
#pragma unroll
    for (int u = 0; u < 16; u += 4) {
      f32x4 v = *(const f32x4*)(src + u);
      lt[rr][cg + u + 0] = (__bf16)v[0];
      lt[rr][cg + u + 1] = (__bf16)v[1];
      lt[rr][cg + u + 2] = (__bf16)v[2];
      lt[rr][cg + u + 3] = (__bf16)v[3];
    }
  }
  __syncthreads();
  {
    const int cc = tid >> 2, rg = (tid & 3) * 16;
    bf16x8 o0, o1;
#pragma unroll
    for (int e = 0; e < 8; ++e) o0[e] = lt[rg + e][cc];
#pragma unroll
    for (int e = 0; e < 8; ++e) o1[e] = lt[rg + 8 + e][cc];
    __bf16* dst = &out[(size_t)(c0 + cc) * 256 + r0 + rg];
    *(bf16x8*)(dst) = o0;
    *(bf16x8*)(dst + 8) = o1;
  }
}

// ---------------- W2T = wxT @ emb_w^T : [256 h][8000 v] bf16 ----------------
__global__ __launch_bounds__(512) void k_w2m(const __bf16* __restrict__ wxT,
                                             const float* __restrict__ emb_w,
                                             __bf16* __restrict__ w2t) {
  __shared__ __bf16 sA[256 * 64];  // [h][k] ^ ((h&7)<<3)
  __shared__ __bf16 sB[64 * 64];   // [v][k] ^ ((v&7)<<3)
  const int tid = threadIdx.x;
  const int v0 = blockIdx.x * 64;
  const int lane = tid & 63;
  const int w = tid >> 6;
  const int wm = w >> 1, wn = w & 1;
  const int l16 = lane & 15, lk = lane >> 4;

  const int arow = tid >> 1, aks = (tid & 1) * 32;
  const int br = tid >> 3, bkc = (tid & 7) * 8;

  f32x4 acc[4][2] = {};

  for (int it = 0; it < 4; ++it) {
    const int kb = it * 64;
    __syncthreads();
    {
      const __bf16* ap = &wxT[(size_t)arow * 256 + kb + aks];
      const int wbase = (arow * 64 + aks);
      const int sw = (arow & 7) << 3;
#pragma unroll
      for (int m = 0; m < 4; ++m)
        *(bf16x8*)&sA[(wbase + m * 8) ^ sw] = *(const bf16x8*)(ap + m * 8);
      const float* bp = &emb_w[(size_t)(v0 + br) * 256 + kb + bkc];
      f32x4 x0 = *(const f32x4*)(bp);
      f32x4 x1 = *(const f32x4*)(bp + 4);
      bf16x8 bw;
      bw[0] = (__bf16)x0[0]; bw[1] = (__bf16)x0[1]; bw[2] = (__bf16)x0[2]; bw[3] = (__bf16)x0[3];
      bw[4] = (__bf16)x1[0]; bw[5] = (__bf16)x1[1]; bw[6] = (__bf16)x1[2]; bw[7] = (__bf16)x1[3];
      *(bf16x8*)&sB[(br * 64 + bkc) ^ ((br & 7) << 3)] = bw;
    }
    __syncthreads();
#pragma unroll
    for (int s = 0; s < 2; ++s) {
      bf16x8 af[4], bfr[2];
#pragma unroll
      for (int i = 0; i < 4; ++i) {
        const int r = wm * 64 + i * 16 + l16;
        af[i] = *(const bf16x8*)&sA[(r * 64 + s * 32 + lk * 8) ^ ((r & 7) << 3)];
      }
#pragma unroll
      for (int j = 0; j < 2; ++j) {
        const int c = wn * 32 + j * 16 + l16;
        bfr[j] = *(const bf16x8*)&sB[(c * 64 + s * 32 + lk * 8) ^ ((c & 7) << 3)];
      }
#pragma unroll
      for (int i = 0; i < 4; ++i)
#pragma unroll
        for (int j = 0; j < 2; ++j)
          acc[i][j] = __builtin_amdgcn_mfma_f32_16x16x32_bf16(af[i], bfr[j], acc[i][j], 0, 0, 0);
    }
  }

#pragma unroll
  for (int i = 0; i < 4; ++i)
#pragma unroll
    for (int j = 0; j < 2; ++j)
#pragma unroll
      for (int e = 0; e < 4; ++e) {
        const int h = wm * 64 + i * 16 + lk * 4 + e;
        const int v = v0 + wn * 32 + j * 16 + l16;
        w2t[(size_t)h * 8000 + v] = (__bf16)acc[i][j][e];
      }
}

// ---------------- embedding GEMM: part[kc] = inputs @ W2 ----------------
__global__ __launch_bounds__(512) void k_embed_gemm2(const float* __restrict__ inp,
                                                     const __bf16* __restrict__ w2t,
                                                     float* __restrict__ part) {
  __shared__ __bf16 sA[2][32 * 64];   // 8 KB
  __shared__ __bf16 sB[2][256 * 64];  // 64 KB
  const int tid = threadIdx.x;
  const int m0 = blockIdx.x * 32;
  const int kc = blockIdx.y;
  const size_t kbase = (size_t)kc * KCH;
  const int lane = tid & 63;
  const int w = tid >> 6;
  const int wm = w >> 2, wn = w & 3;
  const int l16 = lane & 15, lk = lane >> 4;

  const int ar = tid >> 4, ac = (tid & 15) * 4;
  const int bc = tid >> 1, bk = (tid & 1) * 32;
  const int aswz = (ar & 7) << 3;
  const int bswz = (bc & 7) << 3;

  const float* aptr = &inp[(size_t)(m0 + ar) * 8000 + kbase + ac];
  const __bf16* bptr = &w2t[(size_t)bc * 8000 + kbase + bk];

  f32x4 acc[4] = {};
  f32x4 a0;
  bf16x8 b0, b1, b2, b3;

  a0 = *(const f32x4*)(aptr);
  b0 = *(const bf16x8*)(bptr);
  b1 = *(const bf16x8*)(bptr + 8);
  b2 = *(const bf16x8*)(bptr + 16);
  b3 = *(const bf16x8*)(bptr + 24);
  {
    bf16x4 aw;
    aw[0] = (__bf16)a0[0]; aw[1] = (__bf16)a0[1]; aw[2] = (__bf16)a0[2]; aw[3] = (__bf16)a0[3];
    *(bf16x4*)&sA[0][(ar * 64 + ac) ^ aswz] = aw;
    *(bf16x8*)&sB[0][(bc * 64 + bk + 0) ^ bswz] = b0;
    *(bf16x8*)&sB[0][(bc * 64 + bk + 8) ^ bswz] = b1;
    *(bf16x8*)&sB[0][(bc * 64 + bk + 16) ^ bswz] = b2;
    *(bf16x8*)&sB[0][(bc * 64 + bk + 24) ^ bswz] = b3;
  }
  a0 = *(const f32x4*)(aptr + 64);
  b0 = *(const bf16x8*)(bptr + 64);
  b1 = *(const bf16x8*)(bptr + 72);
  b2 = *(const bf16x8*)(bptr + 80);
  b3 = *(const bf16x8*)(bptr + 88);
  __syncthreads();

  for (int it = 0; it < NITER; ++it) {
    const int cur = it & 1;
    if (it + 1 < NITER) {
      bf16x4 aw;
      aw[0] = (__bf16)a0[0]; aw[1] = (__bf16)a0[1]; aw[2] = (__bf16)a0[2]; aw[3] = (__bf16)a0[3];
      *(bf16x4*)&sA[cur ^ 1][(ar * 64 + ac) ^ aswz] = aw;
      *(bf16x8*)&sB[cur ^ 1][(bc * 64 + bk + 0) ^ bswz] = b0;
      *(bf16x8*)&sB[cur ^ 1][(bc * 64 + bk + 8) ^ bswz] = b1;
      *(bf16x8*)&sB[cur ^ 1][(bc * 64 + bk + 16) ^ bswz] = b2;
      *(bf16x8*)&sB[cur ^ 1][(bc * 64 + bk + 24) ^ bswz] = b3;
    }
    if (it + 2 < NITER) {
      const float* ap = aptr + (size_t)(it + 2) * 64;
      const __bf16* bp = bptr + (size_t)(it + 2) * 64;
      a0 = *(const f32x4*)(ap);
      b0 = *(const bf16x8*)(bp);
      b1 = *(const bf16x8*)(bp + 8);
      b2 = *(const bf16x8*)(bp + 16);
      b3 = *(const bf16x8*)(bp + 24);
    }
#pragma unroll
    for (int s = 0; s < 2; ++s) {
      bf16x8 af, bfb[4];
      {
        const int r = wm * 16 + l16;
        af = *(const bf16x8*)&sA[cur][(r * 64 + s * 32 + lk * 8) ^ ((r & 7) << 3)];
      }
#pragma unroll
      for (int j = 0; j < 4; ++j) {
        const int c = wn * 64 + j * 16 + l16;
        bfb[j] = *(const bf16x8*)&sB[cur][(c * 64 + s * 32 + lk * 8) ^ ((c & 7) << 3)];
      }
#pragma unroll
      for (int j = 0; j < 4; ++j)
        acc[j] = __builtin_amdgcn_mfma_f32_16x16x32_bf16(af, bfb[j], acc[j], 0, 0, 0);
    }
    __syncthreads();
  }

#pragma unroll
  for (int j = 0; j < 4; ++j)
#pragma unroll
    for (int e = 0; e < 4; ++e) {
      const int gr = m0 + wm * 16 + lk * 4 + e;
      const int gc = wn * 64 + j * 16 + l16;
      part[((size_t)kc * 4096 + gr) * 256 + gc] = acc[j][e];
    }
}

// ---------------- reduce partials + c2 -> xw4[b][t][h] ----------------
__global__ __launch_bounds__(256) void k_reduce2(const float* __restrict__ part,
                                                 const float* __restrict__ c2,
                                                 float* __restrict__ xw4) {
  const int m0 = blockIdx.x * 16;
  const int h = threadIdx.x;
  const float cv = c2[h];
#pragma unroll
  for (int mi = 0; mi < 16; ++mi) {
    const int m = m0 + mi;
    float s = cv;
#pragma unroll
    for (int c = 0; c < KSPLIT; ++c) s += part[((size_t)c * 4096 + m) * 256 + h];
    const int b = m >> 9, t = m & 511;
    xw4[((size_t)b * 512 + t) * 256 + h] = s;
  }
}

// ---------------- sequential RNN scan: per-batch, 8 blocks, 512 steps ----------------
// 4 waves; wave w owns cols [w*64, w*64+64) as 4 16-col MFMA tiles.
// h double-buffered in LDS bf16[2][256]; A-frag row 0 only (l16==0 lanes).
// 4 independent MFMA chains of depth 2 (p0..p3), tree-add -> shortest result latency.
// xv folded into C-init of chain 0; one raw barrier/step; xw prefetch distance-2.
__global__ __launch_bounds__(256, 1) void k_rnn_scan(const __bf16* __restrict__ whT,
                                                     const float* __restrict__ xw4,
                                                     float* __restrict__ hT) {
  __shared__ __bf16 h2[2][256];
  const int tid = threadIdx.x;
  const int lane = tid & 63;
  const int w = tid >> 6;            // 0..3
  const int l16 = lane & 15, lk = lane >> 4;
  const int b = blockIdx.x;
  const bool act = (l16 == 0);
  const bool oact = (lk == 0);
  const int colb = w * 64 + l16;

  bf16x8 whB[4][8];
#pragma unroll
  for (int j = 0; j < 4; ++j) {
    const int col = colb + j * 16;
#pragma unroll
    for (int s = 0; s < 8; ++s)
      whB[j][s] = *(const bf16x8*)&whT[(size_t)col * 256 + s * 32 + lk * 8];
  }

  h2[0][tid] = (__bf16)0.0f;

  const float* xwb = &xw4[(size_t)b * 512 * 256];
  float xvA[4], xvB[4], nA[4], nB[4];
#pragma unroll
  for (int j = 0; j < 4; ++j) {
    xvA[j] = xwb[0 * 256 + colb + j * 16];
    xvB[j] = xwb[1 * 256 + colb + j * 16];
  }

  bf16x8 af[8];
#pragma unroll
  for (int s = 0; s < 8; ++s) af[s] = bf16x8{};

  __syncthreads();

#define RNN_STEP(RD, WR, XV, LAST_T)                                              \
  {                                                                               \
    if (act) {                                                                    \
      _Pragma("unroll") for (int s = 0; s < 8; ++s)                               \
          af[s] = *(const bf16x8*)&h2[RD][s * 32 + lk * 8];                       \
    }                                                                             \
    float hn[4];                                                                  \
    _Pragma("unroll") for (int j = 0; j < 4; ++j) {                               \
      f32x4 p0 = {}, p1 = {}, p2 = {}, p3 = {};                                   \
      p0[0] = oact ? (XV)[j] : 0.0f;                                              \
      p0 = __builtin_amdgcn_mfma_f32_16x16x32_bf16(af[0], whB[j][0], p0, 0, 0, 0);\
      p1 = __builtin_amdgcn_mfma_f32_16x16x32_bf16(af[1], whB[j][1], p1, 0, 0, 0);\
      p2 = __builtin_amdgcn_mfma_f32_16x16x32_bf16(af[2], whB[j][2], p2, 0, 0, 0);\
      p3 = __builtin_amdgcn_mfma_f32_16x16x32_bf16(af[3], whB[j][3], p3, 0, 0, 0);\
      p0 = __builtin_amdgcn_mfma_f32_16x16x32_bf16(af[4], whB[j][4], p0, 0, 0, 0);\
      p1 = __builtin_amdgcn_mfma_f32_16x16x32_bf16(af[5], whB[j][5], p1, 0, 0, 0);\
      p2 = __builtin_amdgcn_mfma_f32_16x16x32_bf16(af[6], whB[j][6], p2, 0, 0, 0);\
      p3 = __builtin_amdgcn_mfma_f32_16x16x32_bf16(af[7], whB[j][7], p3, 0, 0, 0);\
      const float v = (p0[0] + p1[0]) + (p2[0] + p3[0]);                          \
      const float e2 = __builtin_amdgcn_exp2f(v * 2.8853900817779268f);           \
      hn[j] = __builtin_fmaf(-2.0f, __builtin_amdgcn_rcpf(e2 + 1.0f), 1.0f);      \
    }                                                                             \
    if (oact) {                                                                   \
      _Pragma("unroll") for (int j = 0; j < 4; ++j) {                             \
        h2[WR][colb + j * 16] = (__bf16)hn[j];                                    \
        if (LAST_T) hT[b * 256 + colb + j * 16] = hn[j];                          \
      }                                                                           \
    }                                                                             \
    asm volatile("s_waitcnt lgkmcnt(0)" ::: "memory");                            \
    __builtin_amdgcn_sched_barrier(0);                                            \
    __builtin_amdgcn_s_barrier();                                                 \
    __builtin_amdgcn_sched_barrier(0);                                            \
  }

  for (int tt = 0; tt < 256; ++tt) {
    const int tg = tt * 2;
    const bool more = (tt < 255);
    if (more) {
#pragma unroll
      for (int j = 0; j < 4; ++j) nA[j] = xwb[(size_t)(tg + 2) * 256 + colb + j * 16];
    }
    RNN_STEP(0, 1, xvA, false)
    if (more) {
#pragma unroll
      for (int j = 0; j < 4; ++j) nB[j] = xwb[(size_t)(tg + 3) * 256 + colb + j * 16];
    }
    RNN_STEP(1, 0, xvB, (tt == 255))
    if (more) {
#pragma unroll
      for (int j = 0; j < 4; ++j) { xvA[j] = nA[j]; xvB[j] = nB[j]; }
    }
  }
#undef RNN_STEP
}

// ---------------- logits: raw logits (+out_b) -> ws, 64 blocks ----------------
__global__ __launch_bounds__(256) void k_logits(const float* __restrict__ hT,
                                                const float* __restrict__ out_w,
                                                const float* __restrict__ out_b,
                                                float* __restrict__ logits) {
  __shared__ float hs[256];
  const int vc = blockIdx.x, b = blockIdx.y;
  const int tid = threadIdx.x;
  hs[tid] = hT[b * 256 + tid];
  __syncthreads();

  const int v0 = vc * 1024 + tid * 4;
  if (v0 >= 8000) return;
  f32x4 acc = *(const f32x4*)&out_b[v0];
#pragma unroll 8
  for (int k = 0; k < 256; ++k) {
    acc += hs[k] * (*(const f32x4*)&out_w[(size_t)k * 8000 + v0]);
  }
  *(f32x4*)&logits[(size_t)b * 8192 + v0] = acc;
}

// ---------------- softmax over precomputed logits, 8 blocks ----------------
__global__ __launch_bounds__(1024) void k_softmax8(const float* __restrict__ logits,
                                                   float* __restrict__ out) {
  __shared__ float red[16];
  const int b = blockIdx.x;
  const int tid = threadIdx.x;
  const bool active = tid < 1000;
  const int v0 = tid * 8;
  f32x4 acc0 = {}, acc1 = {};
  if (active) {
    acc0 = *(const f32x4*)&logits[(size_t)b * 8192 + v0];
    acc1 = *(const f32x4*)&logits[(size_t)b * 8192 + v0 + 4];
  }

  float m = -__builtin_huge_valf();
  if (active) {
#pragma unroll
    for (int e = 0; e < 4; ++e) m = fmaxf(m, fmaxf(acc0[e], acc1[e]));
  }
#pragma unroll
  for (int off = 32; off > 0; off >>= 1) m = fmaxf(m, __shfl_xor(m, off));
  if ((tid & 63) == 0) red[tid >> 6] = m;
  __syncthreads();
  if (tid < 64) {
    float t = (tid < 16) ? red[tid] : -__builtin_huge_valf();
#pragma unroll
    for (int off = 8; off > 0; off >>= 1) t = fmaxf(t, __shfl_xor(t, off));
    if (tid == 0) red[0] = t;
  }
  __syncthreads();
  const float M = red[0];

  f32x4 e0 = {}, e1 = {};
  float s = 0.0f;
  if (active) {
#pragma unroll
    for (int e = 0; e < 4; ++e) {
      e0[e] = __expf(acc0[e] - M);
      e1[e] = __expf(acc1[e] - M);
      s += e0[e] + e1[e];
    }
  }
#pragma unroll
  for (int off = 32; off > 0; off >>= 1) s += __shfl_xor(s, off);
  if ((tid & 63) == 0) red[tid >> 6] = s;
  __syncthreads();
  if (tid < 64) {
    float t = (tid < 16) ? red[tid] : 0.0f;
#pragma unroll
    for (int off = 8; off > 0; off >>= 1) t += __shfl_xor(t, off);
    if (tid == 0) red[0] = t;
  }
  __syncthreads();
  const float inv = 1.0f / red[0];

  if (active) {
    float* op = &out[(size_t)b * 8000 + v0];
    *(f32x4*)(op) = e0 * inv;
    *(f32x4*)(op + 4) = e1 * inv;
  }
}

// ---------------- launch ----------------
extern "C" void kernel_launch(void* const* d_in, const int* in_sizes, int n_in,
                              void* d_out, int out_size, void* d_ws, size_t ws_size,
                              hipStream_t stream) {
  const float* inputs = (const float*)d_in[0];  // (8,512,8000)
  const float* emb_w  = (const float*)d_in[1];  // (8000,256)
  const float* emb_b  = (const float*)d_in[2];  // (256)
  const float* wx     = (const float*)d_in[3];  // (256,256)
  const float* wh     = (const float*)d_in[4];  // (256,256)
  const float* hb     = (const float*)d_in[5];  // (1,256)
  const float* out_w  = (const float*)d_in[6];  // (256,8000)
  const float* out_b  = (const float*)d_in[7];  // (8000)
  float* out = (float*)d_out;                   // (8,1,8000)

  char* ws = (char*)d_ws;
  __bf16* whT   = (__bf16*)(ws + 0);             //   131,072
  __bf16* wxT   = (__bf16*)(ws + 131072);        //   131,072
  __bf16* w2t   = (__bf16*)(ws + 262144);        // 4,096,000  (256 x 8000 bf16)
  float* part   = (float*)(ws + 4358144);        // 20,971,520 (5 x 4096 x 256 f32)
  float* xw4    = (float*)(ws + 25329664);       // 4,194,304  ([8][512][256] f32)
  float* hT     = (float*)(ws + 29523968);       //     8,192
  float* c2     = (float*)(ws + 29532160);       //     1,024
  float* logits = (float*)(ws + 29533184);       //   262,144

  k_prep<<<33, 256, 0, stream>>>(wh, wx, emb_b, hb, whT, wxT, c2);
  k_w2m<<<125, 512, 0, stream>>>(wxT, emb_w, w2t);
  k_embed_gemm2<<<dim3(128, KSPLIT), 512, 0, stream>>>(inputs, w2t, part);
  k_reduce2<<<256, 256, 0, stream>>>(part, c2, xw4);
  k_rnn_scan<<<8, 256, 0, stream>>>(whT, xw4, hT);
  k_logits<<<dim3(8, 8), 256, 0, stream>>>(hT, out_w, out_b, logits);
  k_softmax8<<<8, 1024, 0, stream>>>(logits, out);
}